// Round 2
// baseline (20377.380 us; speedup 1.0000x reference)
//
#include <hip/hip_runtime.h>
#include <hip/hip_bf16.h>
#include <stdint.h>

#define T_STEPS 512
#define NBATCH 64
#define HID 1024
#define NGATE 4096
#define NLAYERS 2
#define TCHUNK 128
#define BH (NBATCH * HID)            // 65536
#define TBH (T_STEPS * NBATCH * HID) // 33554432
#define WEL ((size_t)NLAYERS * NGATE * HID)
#define NBLK 256

typedef __attribute__((ext_vector_type(8))) short short8;
typedef __attribute__((ext_vector_type(4))) float f32x4;

__device__ __forceinline__ ushort f2bf(float f) {
  union { float f; uint32_t i; } u; u.f = f;
  return (ushort)((u.i + 0x7fffu + ((u.i >> 16) & 1u)) >> 16);  // RNE
}
__device__ __forceinline__ float bf2f(ushort b) {
  union { uint32_t i; float f; } u; u.i = ((uint32_t)b) << 16;
  return u.f;
}
__device__ __forceinline__ void gll16(const void* g, void* l) {
  __builtin_amdgcn_global_load_lds(
      (const __attribute__((address_space(1))) unsigned int*)g,
      (__attribute__((address_space(3))) unsigned int*)l, 16, 0, 0);
}

// ---------------- elementwise helpers ----------------
__global__ void k_f32_to_bf16(const float* __restrict__ in, ushort* __restrict__ out, int n) {
  int i = (blockIdx.x * blockDim.x + threadIdx.x) * 4;
  if (i >= n) return;
  const float4 v = *reinterpret_cast<const float4*>(in + i);
  ushort4 o; o.x = f2bf(v.x); o.y = f2bf(v.y); o.z = f2bf(v.z); o.w = f2bf(v.w);
  *reinterpret_cast<ushort4*>(out + i) = o;
}
__global__ void k_copy_f32(const float* __restrict__ in, float* __restrict__ out, int n) {
  int i = (blockIdx.x * blockDim.x + threadIdx.x) * 4;
  if (i >= n) return;
  *reinterpret_cast<float4*>(out + i) = *reinterpret_cast<const float4*>(in + i);
}
__global__ void k_zero2(int* p) { if (threadIdx.x < 2) p[threadIdx.x] = 0; }

// ---------------- igates GEMM (layer 0 only): C(8192,4096) = A @ W_ih0^T + b ----------------
__global__ __launch_bounds__(256) void k_gemm_ig(
    const ushort* __restrict__ A, const ushort* __restrict__ W,
    const float* __restrict__ bia, const float* __restrict__ bib,
    ushort* __restrict__ C)
{
  __shared__ __align__(16) ushort At[128 * 64];
  __shared__ __align__(16) ushort Bt[128 * 64];
  const int tid = threadIdx.x;
  const int wave = tid >> 6, lane = tid & 63;
  const int m0 = blockIdx.x * 128;
  const int n0 = blockIdx.y * 128;
  const int wr = wave >> 1, wc = wave & 1;

  const int r_st = wave * 8 + (lane >> 3);
  const int bsw = ((lane & 7) * 16) ^ ((r_st & 7) << 4);
  const ushort* aSrc = A + (size_t)(m0 + r_st) * 1024 + (bsw >> 1);
  const ushort* bSrc = W + (size_t)(n0 + r_st) * 1024 + (bsw >> 1);
  ushort* aDst = At + wave * 512;
  ushort* bDst = Bt + wave * 512;

  f32x4 acc[4][4];
#pragma unroll
  for (int a = 0; a < 4; ++a)
#pragma unroll
    for (int b = 0; b < 4; ++b) acc[a][b] = (f32x4){0.f, 0.f, 0.f, 0.f};

  for (int ks = 0; ks < 16; ++ks) {
#pragma unroll
    for (int i = 0; i < 4; ++i) {
      gll16(aSrc + (size_t)i * 32 * 1024 + ks * 64, aDst + i * 2048);
      gll16(bSrc + (size_t)i * 32 * 1024 + ks * 64, bDst + i * 2048);
    }
    __syncthreads();
#pragma unroll
    for (int kc = 0; kc < 2; ++kc) {
      const int kb = kc * 64 + (lane >> 4) * 16;
      short8 af[4], bfr[4];
#pragma unroll
      for (int mt = 0; mt < 4; ++mt) {
        const int r = wr * 64 + mt * 16 + (lane & 15);
        af[mt] = *(const short8*)((const char*)At + r * 128 + (kb ^ ((r & 7) << 4)));
      }
#pragma unroll
      for (int nt = 0; nt < 4; ++nt) {
        const int r = wc * 64 + nt * 16 + (lane & 15);
        bfr[nt] = *(const short8*)((const char*)Bt + r * 128 + (kb ^ ((r & 7) << 4)));
      }
#pragma unroll
      for (int mt = 0; mt < 4; ++mt)
#pragma unroll
        for (int nt = 0; nt < 4; ++nt)
          acc[mt][nt] = __builtin_amdgcn_mfma_f32_16x16x32_bf16(af[mt], bfr[nt], acc[mt][nt], 0, 0, 0);
    }
    __syncthreads();
  }

#pragma unroll
  for (int nt = 0; nt < 4; ++nt) {
    const int col = n0 + wc * 64 + nt * 16 + (lane & 15);
    const float bias = bia[col] + bib[col];
#pragma unroll
    for (int mt = 0; mt < 4; ++mt) {
      const int row = m0 + wr * 64 + mt * 16 + (lane >> 4) * 4;
      const f32x4 v = acc[mt][nt];
#pragma unroll
      for (int r = 0; r < 4; ++r)
        C[(size_t)(row + r) * 4096 + col] = f2bf(v[r] + bias);
    }
  }
}

// ---------------- persistent pipelined scan ----------------
struct ScanP {
  const ushort* wih1; const ushort* whh0; const ushort* whh1;
  const ushort* ig;   const ushort* hinit;
  ushort* h0r; ushort* h1r; float* cbuf;
  const float* bi1; const float* bh1;
  float* out; int* bar; int s0; int s1;
};

__device__ __forceinline__ void gbar(int* bar) {
  __syncthreads();                       // block's stores drained to L2 (vmcnt 0)
  if (threadIdx.x == 0) {
    __threadfence();                     // release: L2 -> coherence point
    int gen = __hip_atomic_load(bar + 1, __ATOMIC_RELAXED, __HIP_MEMORY_SCOPE_AGENT);
    int a = __hip_atomic_fetch_add(bar, 1, __ATOMIC_ACQ_REL, __HIP_MEMORY_SCOPE_AGENT);
    if (a == NBLK - 1) {
      __hip_atomic_store(bar, 0, __ATOMIC_RELAXED, __HIP_MEMORY_SCOPE_AGENT);
      __hip_atomic_store(bar + 1, gen + 1, __ATOMIC_RELEASE, __HIP_MEMORY_SCOPE_AGENT);
    } else {
      while (__hip_atomic_load(bar + 1, __ATOMIC_RELAXED, __HIP_MEMORY_SCOPE_AGENT) == gen)
        __builtin_amdgcn_s_sleep(4);
    }
    __threadfence();                     // acquire: invalidate L1/L2 for fresh h reads
  }
  __syncthreads();
}

// 256 blocks x 256 threads. Blocks 0..127: layer0 step s (K=1024, igates precomputed).
// Blocks 128..255: layer1 step s-1 (K=2048 fused [W_ih1|W_hh1], A = [h0_{s-1} ; h1_{s-2}]).
// Each block owns 8 h-cols x 4 gates = 32 gate rows; W rows in LDS, XOR-swizzled, stride 4096B.
__global__ __launch_bounds__(256, 1) void k_scan(ScanP p) {
  __shared__ __align__(16) ushort Wl[32 * 2048];  // 128 KB
  __shared__ float glds[64 * 33];                 // 8.4 KB
  const int tid = threadIdx.x, wave = tid >> 6, lane = tid & 63;
  const bool isL1 = blockIdx.x >= 128;
  const int cb = isL1 ? (int)blockIdx.x - 128 : (int)blockIdx.x;
  const int j0 = cb * 8;

  // ---- stage W once: LDS row i = gate*8+jl; row bytes [0,2048)=K 0..1023, [2048,4096)=K 1024..2047
  if (isL1) {
    for (int q = wave; q < 128; q += 4) {
      const int i = q >> 2, ch = q & 3;
      const ushort* base = (ch < 2) ? p.wih1 : p.whh1;
      const int g = (i >> 3) * 1024 + j0 + (i & 7);
      gll16(base + (size_t)g * 1024 + (ch & 1) * 512 + (((lane * 16) ^ ((i & 7) << 4)) >> 1),
            (char*)Wl + i * 4096 + ch * 1024);
    }
  } else {
    for (int q = wave; q < 64; q += 4) {
      const int i = q >> 1, ch = q & 1;
      const int g = (i >> 3) * 1024 + j0 + (i & 7);
      gll16(p.whh0 + (size_t)g * 1024 + ch * 512 + (((lane * 16) ^ ((i & 7) << 4)) >> 1),
            (char*)Wl + i * 4096 + ch * 1024);
    }
  }

  // ---- per-thread nonlinearity geometry, c in registers ----
  const int jl = tid & 7, j = j0 + jl;
  float* cb_ = p.cbuf + (isL1 ? BH : 0);
  float creg[2], bias[4] = {0.f, 0.f, 0.f, 0.f};
#pragma unroll
  for (int i = 0; i < 2; ++i) creg[i] = cb_[((tid + 256 * i) >> 3) * 1024 + j];
  if (isL1) {
#pragma unroll
    for (int g = 0; g < 4; ++g) bias[g] = p.bi1[g * 1024 + j] + p.bh1[g * 1024 + j];
  }

  // ---- MFMA lane geometry (16x16x32): wave owns batch rows [wave*16, wave*16+16) ----
  const size_t aoff = (size_t)(wave * 16 + (lane & 15)) * 1024 + (size_t)((lane >> 4) * 8);
  const int r0 = lane & 15;
  const char* bb0 = (const char*)Wl + r0 * 4096;
  const char* bb1 = (const char*)Wl + (r0 + 16) * 4096;
  const int bsw = (r0 & 7) << 4;
  const int kb = (lane >> 4) * 16;

  __syncthreads();  // W staged (vmcnt drained by barrier)

  for (int s = p.s0; s < p.s1; ++s) {
    const bool act = isL1 ? (s >= 1) : (s < T_STEPS);
    if (act) {
      f32x4 accA = {0.f, 0.f, 0.f, 0.f}, accB = {0.f, 0.f, 0.f, 0.f};
      if (!isL1) {
        const ushort* h = (s == 0) ? p.hinit : p.h0r + (size_t)((s - 1) & 1) * BH;
#pragma unroll 8
        for (int kc = 0; kc < 32; ++kc) {
          short8 av  = *(const short8*)(h + aoff + kc * 32);
          short8 b0v = *(const short8*)(bb0 + ((kc * 64 + kb) ^ bsw));
          short8 b1v = *(const short8*)(bb1 + ((kc * 64 + kb) ^ bsw));
          accA = __builtin_amdgcn_mfma_f32_16x16x32_bf16(av, b0v, accA, 0, 0, 0);
          accB = __builtin_amdgcn_mfma_f32_16x16x32_bf16(av, b1v, accB, 0, 0, 0);
        }
      } else {
        const ushort* h0p = p.h0r + (size_t)((s - 1) & 1) * BH;
        const ushort* h1p = (s == 1) ? p.hinit + BH : p.h1r + (size_t)(s & 1) * BH;
#pragma unroll 8
        for (int kc = 0; kc < 32; ++kc) {
          short8 av  = *(const short8*)(h0p + aoff + kc * 32);
          short8 b0v = *(const short8*)(bb0 + ((kc * 64 + kb) ^ bsw));
          short8 b1v = *(const short8*)(bb1 + ((kc * 64 + kb) ^ bsw));
          accA = __builtin_amdgcn_mfma_f32_16x16x32_bf16(av, b0v, accA, 0, 0, 0);
          accB = __builtin_amdgcn_mfma_f32_16x16x32_bf16(av, b1v, accB, 0, 0, 0);
        }
#pragma unroll 8
        for (int kc = 32; kc < 64; ++kc) {
          short8 av  = *(const short8*)(h1p + aoff + (kc - 32) * 32);
          short8 b0v = *(const short8*)(bb0 + ((kc * 64 + kb) ^ bsw));
          short8 b1v = *(const short8*)(bb1 + ((kc * 64 + kb) ^ bsw));
          accA = __builtin_amdgcn_mfma_f32_16x16x32_bf16(av, b0v, accA, 0, 0, 0);
          accB = __builtin_amdgcn_mfma_f32_16x16x32_bf16(av, b1v, accB, 0, 0, 0);
        }
      }
      // C layout 16x16: col=lane&15, row=(lane>>4)*4+reg  -> glds[batch][gatecol 0..31]
#pragma unroll
      for (int r = 0; r < 4; ++r) {
        const int row = wave * 16 + (lane >> 4) * 4 + r;
        glds[row * 33 + r0]      = accA[r];
        glds[row * 33 + 16 + r0] = accB[r];
      }
      __syncthreads();

      const ushort* ig_ = p.ig + (size_t)(s & (TCHUNK - 1)) * (NBATCH * NGATE);
#pragma unroll
      for (int i = 0; i < 2; ++i) {
        const int b = (tid + 256 * i) >> 3;
        float gi, gf, gg, go;
        if (!isL1) {
          gi = glds[b * 33 + jl]      + bf2f(ig_[b * 4096 + j]);
          gf = glds[b * 33 + 8 + jl]  + bf2f(ig_[b * 4096 + 1024 + j]);
          gg = glds[b * 33 + 16 + jl] + bf2f(ig_[b * 4096 + 2048 + j]);
          go = glds[b * 33 + 24 + jl] + bf2f(ig_[b * 4096 + 3072 + j]);
        } else {
          gi = glds[b * 33 + jl]      + bias[0];
          gf = glds[b * 33 + 8 + jl]  + bias[1];
          gg = glds[b * 33 + 16 + jl] + bias[2];
          go = glds[b * 33 + 24 + jl] + bias[3];
        }
        float c = creg[i];
        const float si = 1.f / (1.f + __expf(-gi));
        const float sf = 1.f / (1.f + __expf(-gf));
        const float so = 1.f / (1.f + __expf(-go));
        const float tg = tanhf(gg);
        c = sf * c + si * tg;
        const float h = so * tanhf(c);
        creg[i] = c;
        if (!isL1) {
          (p.h0r + (size_t)(s & 1) * BH)[b * 1024 + j] = f2bf(h);
          if (s == T_STEPS - 1) {
            p.out[(size_t)TBH + b * 1024 + j] = h;
            p.out[(size_t)TBH + 2 * BH + b * 1024 + j] = c;
          }
        } else {
          (p.h1r + (size_t)((s - 1) & 1) * BH)[b * 1024 + j] = f2bf(h);
          p.out[(size_t)(s - 1) * BH + b * 1024 + j] = h;
          if (s - 1 == T_STEPS - 1) {
            p.out[(size_t)TBH + BH + b * 1024 + j] = h;
            p.out[(size_t)TBH + 3 * BH + b * 1024 + j] = c;
          }
        }
      }
    }
    gbar(p.bar);
  }
#pragma unroll
  for (int i = 0; i < 2; ++i) cb_[((tid + 256 * i) >> 3) * 1024 + j] = creg[i];
}

// ---------------- host ----------------
extern "C" void kernel_launch(void* const* d_in, const int* in_sizes, int n_in,
                              void* d_out, int out_size, void* d_ws, size_t ws_size,
                              hipStream_t stream) {
  const float* x    = (const float*)d_in[0];
  const float* h0   = (const float*)d_in[1];
  const float* c0   = (const float*)d_in[2];
  const float* w_ih = (const float*)d_in[3];
  const float* w_hh = (const float*)d_in[4];
  const float* b_ih = (const float*)d_in[5];
  const float* b_hh = (const float*)d_in[6];
  float* out = (float*)d_out;

  ushort* xb    = (ushort*)d_ws;
  ushort* wihb  = xb + (size_t)TBH;
  ushort* whhb  = wihb + WEL;
  ushort* ig    = whhb + WEL;
  ushort* hinit = ig + (size_t)TCHUNK * NBATCH * NGATE;
  ushort* h0r   = hinit + 2 * (size_t)BH;
  ushort* h1r   = h0r + 2 * (size_t)BH;
  float*  cbuf  = (float*)(h1r + 2 * (size_t)BH);
  int*    bar   = (int*)(cbuf + 2 * (size_t)BH);

  const size_t need = ((size_t)TBH + 2 * WEL + (size_t)TCHUNK * NBATCH * NGATE
                       + 6 * (size_t)BH) * 2 + 2 * (size_t)BH * 4 + 64;
  if (ws_size < need) return;  // loud failure: d_out stays poisoned

  { int n = TBH;          k_f32_to_bf16<<<(n / 4 + 255) / 256, 256, 0, stream>>>(x, xb, n); }
  { int n = (int)WEL;     k_f32_to_bf16<<<(n / 4 + 255) / 256, 256, 0, stream>>>(w_ih, wihb, n); }
  { int n = (int)WEL;     k_f32_to_bf16<<<(n / 4 + 255) / 256, 256, 0, stream>>>(w_hh, whhb, n); }
  { int n = 2 * BH;       k_f32_to_bf16<<<(n / 4 + 255) / 256, 256, 0, stream>>>(h0, hinit, n); }
  k_copy_f32<<<(2 * BH / 4 + 255) / 256, 256, 0, stream>>>(c0, cbuf, 2 * BH);
  k_zero2<<<1, 64, 0, stream>>>(bar);

  ScanP sp;
  sp.wih1 = wihb + (size_t)NGATE * HID;
  sp.whh0 = whhb;
  sp.whh1 = whhb + (size_t)NGATE * HID;
  sp.ig = ig; sp.hinit = hinit;
  sp.h0r = h0r; sp.h1r = h1r; sp.cbuf = cbuf;
  sp.bi1 = b_ih + NGATE; sp.bh1 = b_hh + NGATE;
  sp.out = out; sp.bar = bar;

  const int bounds[5] = {0, 128, 256, 384, 513};
  for (int c = 0; c < 4; ++c) {
    k_gemm_ig<<<dim3(64, 32), 256, 0, stream>>>(
        xb + (size_t)c * TCHUNK * NBATCH * HID, wihb, b_ih, b_hh, ig);
    sp.s0 = bounds[c]; sp.s1 = bounds[c + 1];
    void* kp[1] = {&sp};
    hipLaunchCooperativeKernel(reinterpret_cast<void*>(&k_scan),
                               dim3(NBLK), dim3(256), kp, 0, stream);
  }
}

// Round 5
// 11442.311 us; speedup vs baseline: 1.7809x; 1.7809x over previous
//
#include <hip/hip_runtime.h>
#include <hip/hip_bf16.h>
#include <stdint.h>

#define T_STEPS 512
#define NBATCH 64
#define HID 1024
#define NGATE 4096
#define NLAYERS 2
#define TCHUNK 128
#define BH (NBATCH * HID)            // 65536
#define TBH (T_STEPS * NBATCH * HID) // 33554432
#define WEL ((size_t)NLAYERS * NGATE * HID)
#define NBLK 256

typedef __attribute__((ext_vector_type(8))) short short8;
typedef __attribute__((ext_vector_type(4))) float f32x4;

__device__ __forceinline__ ushort f2bf(float f) {
  union { float f; uint32_t i; } u; u.f = f;
  return (ushort)((u.i + 0x7fffu + ((u.i >> 16) & 1u)) >> 16);  // RNE
}
__device__ __forceinline__ float bf2f(ushort b) {
  union { uint32_t i; float f; } u; u.i = ((uint32_t)b) << 16;
  return u.f;
}
__device__ __forceinline__ void gll16(const void* g, void* l) {
  __builtin_amdgcn_global_load_lds(
      (const __attribute__((address_space(1))) unsigned int*)g,
      (__attribute__((address_space(3))) unsigned int*)l, 16, 0, 0);
}

// Cross-XCD-coherent h transport: compiler-generated agent-scope relaxed atomics.
// (No inline-asm VMEM: asm outputs under pressure can be spilled before their
// pending global_load writes back -- deterministic corruption. Compiler loads
// are vmcnt-tracked and spill-safe.)
union FragU { unsigned long long u[2]; short8 s8; };
__device__ __forceinline__ short8 ld_frag_sys(const ushort* p) {
  FragU r;
  r.u[0] = __hip_atomic_load((const unsigned long long*)p,       __ATOMIC_RELAXED, __HIP_MEMORY_SCOPE_AGENT);
  r.u[1] = __hip_atomic_load((const unsigned long long*)(p + 4), __ATOMIC_RELAXED, __HIP_MEMORY_SCOPE_AGENT);
  return r.s8;
}

// ---------------- elementwise helpers ----------------
__global__ void k_f32_to_bf16(const float* __restrict__ in, ushort* __restrict__ out, int n) {
  int i = (blockIdx.x * blockDim.x + threadIdx.x) * 4;
  if (i >= n) return;
  const float4 v = *reinterpret_cast<const float4*>(in + i);
  ushort4 o; o.x = f2bf(v.x); o.y = f2bf(v.y); o.z = f2bf(v.z); o.w = f2bf(v.w);
  *reinterpret_cast<ushort4*>(out + i) = o;
}
__global__ void k_copy_f32(const float* __restrict__ in, float* __restrict__ out, int n) {
  int i = (blockIdx.x * blockDim.x + threadIdx.x) * 4;
  if (i >= n) return;
  *reinterpret_cast<float4*>(out + i) = *reinterpret_cast<const float4*>(in + i);
}
__global__ void k_zero(int* p, int n) {
  int i = blockIdx.x * blockDim.x + threadIdx.x;
  if (i < n) p[i] = 0;
}

// ---------------- igates GEMM (layer 0 only): C(8192,4096) = A @ W_ih0^T + b ----------------
__global__ __launch_bounds__(256) void k_gemm_ig(
    const ushort* __restrict__ A, const ushort* __restrict__ W,
    const float* __restrict__ bia, const float* __restrict__ bib,
    ushort* __restrict__ C)
{
  __shared__ __align__(16) ushort At[128 * 64];
  __shared__ __align__(16) ushort Bt[128 * 64];
  const int tid = threadIdx.x;
  const int wave = tid >> 6, lane = tid & 63;
  const int m0 = blockIdx.x * 128;
  const int n0 = blockIdx.y * 128;
  const int wr = wave >> 1, wc = wave & 1;

  const int r_st = wave * 8 + (lane >> 3);
  const int bsw = ((lane & 7) * 16) ^ ((r_st & 7) << 4);
  const ushort* aSrc = A + (size_t)(m0 + r_st) * 1024 + (bsw >> 1);
  const ushort* bSrc = W + (size_t)(n0 + r_st) * 1024 + (bsw >> 1);
  ushort* aDst = At + wave * 512;
  ushort* bDst = Bt + wave * 512;

  f32x4 acc[4][4];
#pragma unroll
  for (int a = 0; a < 4; ++a)
#pragma unroll
    for (int b = 0; b < 4; ++b) acc[a][b] = (f32x4){0.f, 0.f, 0.f, 0.f};

  for (int ks = 0; ks < 16; ++ks) {
#pragma unroll
    for (int i = 0; i < 4; ++i) {
      gll16(aSrc + (size_t)i * 32 * 1024 + ks * 64, aDst + i * 2048);
      gll16(bSrc + (size_t)i * 32 * 1024 + ks * 64, bDst + i * 2048);
    }
    __syncthreads();
#pragma unroll
    for (int kc = 0; kc < 2; ++kc) {
      const int kb = kc * 64 + (lane >> 4) * 16;
      short8 af[4], bfr[4];
#pragma unroll
      for (int mt = 0; mt < 4; ++mt) {
        const int r = wr * 64 + mt * 16 + (lane & 15);
        af[mt] = *(const short8*)((const char*)At + r * 128 + (kb ^ ((r & 7) << 4)));
      }
#pragma unroll
      for (int nt = 0; nt < 4; ++nt) {
        const int r = wc * 64 + nt * 16 + (lane & 15);
        bfr[nt] = *(const short8*)((const char*)Bt + r * 128 + (kb ^ ((r & 7) << 4)));
      }
#pragma unroll
      for (int mt = 0; mt < 4; ++mt)
#pragma unroll
        for (int nt = 0; nt < 4; ++nt)
          acc[mt][nt] = __builtin_amdgcn_mfma_f32_16x16x32_bf16(af[mt], bfr[nt], acc[mt][nt], 0, 0, 0);
    }
    __syncthreads();
  }

#pragma unroll
  for (int nt = 0; nt < 4; ++nt) {
    const int col = n0 + wc * 64 + nt * 16 + (lane & 15);
    const float bias = bia[col] + bib[col];
#pragma unroll
    for (int mt = 0; mt < 4; ++mt) {
      const int row = m0 + wr * 64 + mt * 16 + (lane >> 4) * 4;
      const f32x4 v = acc[mt][nt];
#pragma unroll
      for (int r = 0; r < 4; ++r)
        C[(size_t)(row + r) * 4096 + col] = f2bf(v[r] + bias);
    }
  }
}

// ---------------- persistent pipelined scan ----------------
struct ScanP {
  const ushort* wih1; const ushort* whh0; const ushort* whh1;
  const ushort* ig;   const ushort* hinit;
  ushort* h0r; ushort* h1r; float* cbuf;
  const float* bi1; const float* bh1;
  float* out; int* bar; int s0; int s1;
};

// Monotonic striped barrier (no resets, relaxed-only). Release when
// sum(arrivals) >= (phase+1)*NBLK; max inter-block skew is 1 phase by induction.
// Store visibility is guaranteed by the per-thread same-address load-back of the
// h stores (FIFO per address through the fabric) completing BEFORE __syncthreads,
// which precedes thread 0's arrive in real time.
__device__ __forceinline__ void gbar(int* bar, int phase, int stripe) {
  __syncthreads();
  if (threadIdx.x == 0) {
    __hip_atomic_fetch_add(bar + stripe * 16, 1, __ATOMIC_RELAXED, __HIP_MEMORY_SCOPE_AGENT);
    const int target = (phase + 1) * NBLK;
    for (;;) {
      int sum = 0;
#pragma unroll
      for (int i = 0; i < 16; ++i)
        sum += __hip_atomic_load(bar + i * 16, __ATOMIC_RELAXED, __HIP_MEMORY_SCOPE_AGENT);
      if (sum >= target) break;
      __builtin_amdgcn_s_sleep(4);
    }
  }
  __syncthreads();
  __builtin_amdgcn_sched_barrier(0);
}

// 256 blocks x 256 threads. Blocks 0..127: layer0 step s. Blocks 128..255: layer1 step s-1
// (K=2048 fused [W_ih1|W_hh1], A = [h0_{s-1} ; h1_{s-2}]). W staged once in LDS.
__global__ __launch_bounds__(256, 1) void k_scan(ScanP p) {
  __shared__ __align__(16) ushort Wl[32 * 2048];  // 128 KB
  __shared__ float glds[64 * 33];
  const int tid = threadIdx.x, wave = tid >> 6, lane = tid & 63;
  const bool isL1 = blockIdx.x >= 128;
  const int cb = isL1 ? (int)blockIdx.x - 128 : (int)blockIdx.x;
  const int j0 = cb * 8;
  const int stripe = blockIdx.x & 15;

  if (isL1) {
    for (int q = wave; q < 128; q += 4) {
      const int i = q >> 2, ch = q & 3;
      const ushort* base = (ch < 2) ? p.wih1 : p.whh1;
      const int g = (i >> 3) * 1024 + j0 + (i & 7);
      gll16(base + (size_t)g * 1024 + (ch & 1) * 512 + (((lane * 16) ^ ((i & 7) << 4)) >> 1),
            (char*)Wl + i * 4096 + ch * 1024);
    }
  } else {
    for (int q = wave; q < 64; q += 4) {
      const int i = q >> 1, ch = q & 1;
      const int g = (i >> 3) * 1024 + j0 + (i & 7);
      gll16(p.whh0 + (size_t)g * 1024 + ch * 512 + (((lane * 16) ^ ((i & 7) << 4)) >> 1),
            (char*)Wl + i * 4096 + ch * 1024);
    }
  }

  // Epilogue geometry: thread owns (b = tid>>2, j = j0 + (tid&3)*2 + {0,1})
  const int eb  = tid >> 2;
  const int jl0 = (tid & 3) * 2;
  const int jj  = j0 + jl0;
  float* cb_ = p.cbuf + (isL1 ? BH : 0);
  float creg[2], bias[4][2];
#pragma unroll
  for (int i = 0; i < 2; ++i) creg[i] = cb_[eb * 1024 + jj + i];
  if (isL1) {
#pragma unroll
    for (int g = 0; g < 4; ++g)
#pragma unroll
      for (int i = 0; i < 2; ++i)
        bias[g][i] = p.bi1[g * 1024 + jj + i] + p.bh1[g * 1024 + jj + i];
  }

  const size_t aoff = (size_t)(wave * 16 + (lane & 15)) * 1024 + (size_t)((lane >> 4) * 8);
  const int r0 = lane & 15;
  const char* bb0 = (const char*)Wl + r0 * 4096;
  const char* bb1 = (const char*)Wl + (r0 + 16) * 4096;
  const int bsw = (r0 & 7) << 4;
  const int kb = (lane >> 4) * 16;

  __syncthreads();  // W staged (vmcnt drained)

  for (int s = p.s0; s < p.s1; ++s) {
    const bool act = isL1 ? (s >= 1) : (s < T_STEPS);
    if (act) {
      f32x4 accA = {0.f, 0.f, 0.f, 0.f}, accB = {0.f, 0.f, 0.f, 0.f};
      if (!isL1) {
        const ushort* h = (s == 0) ? p.hinit : p.h0r + (size_t)((s - 1) & 1) * BH;
#pragma unroll 8
        for (int kc = 0; kc < 32; ++kc) {
          short8 av  = ld_frag_sys(h + aoff + kc * 32);
          short8 b0v = *(const short8*)(bb0 + ((kc * 64 + kb) ^ bsw));
          short8 b1v = *(const short8*)(bb1 + ((kc * 64 + kb) ^ bsw));
          accA = __builtin_amdgcn_mfma_f32_16x16x32_bf16(av, b0v, accA, 0, 0, 0);
          accB = __builtin_amdgcn_mfma_f32_16x16x32_bf16(av, b1v, accB, 0, 0, 0);
        }
      } else {
        const ushort* h0p = p.h0r + (size_t)((s - 1) & 1) * BH;
        const ushort* h1p = (s == 1) ? p.hinit + BH : p.h1r + (size_t)(s & 1) * BH;
#pragma unroll 8
        for (int kc = 0; kc < 32; ++kc) {
          short8 av  = ld_frag_sys(h0p + aoff + kc * 32);
          short8 b0v = *(const short8*)(bb0 + ((kc * 64 + kb) ^ bsw));
          short8 b1v = *(const short8*)(bb1 + ((kc * 64 + kb) ^ bsw));
          accA = __builtin_amdgcn_mfma_f32_16x16x32_bf16(av, b0v, accA, 0, 0, 0);
          accB = __builtin_amdgcn_mfma_f32_16x16x32_bf16(av, b1v, accB, 0, 0, 0);
        }
#pragma unroll 8
        for (int kc = 32; kc < 64; ++kc) {
          short8 av  = ld_frag_sys(h1p + aoff + (kc - 32) * 32);
          short8 b0v = *(const short8*)(bb0 + ((kc * 64 + kb) ^ bsw));
          short8 b1v = *(const short8*)(bb1 + ((kc * 64 + kb) ^ bsw));
          accA = __builtin_amdgcn_mfma_f32_16x16x32_bf16(av, b0v, accA, 0, 0, 0);
          accB = __builtin_amdgcn_mfma_f32_16x16x32_bf16(av, b1v, accB, 0, 0, 0);
        }
      }
#pragma unroll
      for (int r = 0; r < 4; ++r) {
        const int row = wave * 16 + (lane >> 4) * 4 + r;
        glds[row * 33 + r0]      = accA[r];
        glds[row * 33 + 16 + r0] = accB[r];
      }
      __syncthreads();

      const ushort* ig_ = p.ig + (size_t)(s & (TCHUNK - 1)) * (NBATCH * NGATE);
      float hres[2];
#pragma unroll
      for (int i = 0; i < 2; ++i) {
        const int jl = jl0 + i;
        float gi, gf, gg, go;
        if (!isL1) {
          gi = glds[eb * 33 + jl]      + bf2f(ig_[eb * 4096 + jj + i]);
          gf = glds[eb * 33 + 8 + jl]  + bf2f(ig_[eb * 4096 + 1024 + jj + i]);
          gg = glds[eb * 33 + 16 + jl] + bf2f(ig_[eb * 4096 + 2048 + jj + i]);
          go = glds[eb * 33 + 24 + jl] + bf2f(ig_[eb * 4096 + 3072 + jj + i]);
        } else {
          gi = glds[eb * 33 + jl]      + bias[0][i];
          gf = glds[eb * 33 + 8 + jl]  + bias[1][i];
          gg = glds[eb * 33 + 16 + jl] + bias[2][i];
          go = glds[eb * 33 + 24 + jl] + bias[3][i];
        }
        float c = creg[i];
        const float si = 1.f / (1.f + __expf(-gi));
        const float sf = 1.f / (1.f + __expf(-gf));
        const float so = 1.f / (1.f + __expf(-go));
        const float tg = tanhf(gg);
        c = sf * c + si * tg;
        hres[i] = so * tanhf(c);
        creg[i] = c;
      }

      const uint32_t packed = (uint32_t)f2bf(hres[0]) | ((uint32_t)f2bf(hres[1]) << 16);
      ushort* hdst = (!isL1) ? (p.h0r + (size_t)(s & 1) * BH)
                             : (p.h1r + (size_t)((s - 1) & 1) * BH);
      uint32_t* hw = (uint32_t*)(hdst + eb * 1024 + jj);
      __hip_atomic_store(hw, packed, __ATOMIC_RELAXED, __HIP_MEMORY_SCOPE_AGENT);
      // Same-address load-back: when this returns, the store is committed at the
      // coherence point (per-address FIFO). Kept live via empty asm (rule 17).
      uint32_t chk = __hip_atomic_load(hw, __ATOMIC_RELAXED, __HIP_MEMORY_SCOPE_AGENT);
      asm volatile("" :: "v"(chk));

      if (isL1) {
#pragma unroll
        for (int i = 0; i < 2; ++i)
          p.out[(size_t)(s - 1) * BH + eb * 1024 + jj + i] = hres[i];
        if (s - 1 == T_STEPS - 1) {
#pragma unroll
          for (int i = 0; i < 2; ++i) {
            p.out[(size_t)TBH + BH + eb * 1024 + jj + i] = hres[i];
            p.out[(size_t)TBH + 3 * BH + eb * 1024 + jj + i] = creg[i];
          }
        }
      } else if (s == T_STEPS - 1) {
#pragma unroll
        for (int i = 0; i < 2; ++i) {
          p.out[(size_t)TBH + eb * 1024 + jj + i] = hres[i];
          p.out[(size_t)TBH + 2 * BH + eb * 1024 + jj + i] = creg[i];
        }
      }
    }
    gbar(p.bar, s - p.s0, stripe);
  }
#pragma unroll
  for (int i = 0; i < 2; ++i) cb_[eb * 1024 + jj + i] = creg[i];
}

// ---------------- host ----------------
extern "C" void kernel_launch(void* const* d_in, const int* in_sizes, int n_in,
                              void* d_out, int out_size, void* d_ws, size_t ws_size,
                              hipStream_t stream) {
  const float* x    = (const float*)d_in[0];
  const float* h0   = (const float*)d_in[1];
  const float* c0   = (const float*)d_in[2];
  const float* w_ih = (const float*)d_in[3];
  const float* w_hh = (const float*)d_in[4];
  const float* b_ih = (const float*)d_in[5];
  const float* b_hh = (const float*)d_in[6];
  float* out = (float*)d_out;

  ushort* xb    = (ushort*)d_ws;
  ushort* wihb  = xb + (size_t)TBH;
  ushort* whhb  = wihb + WEL;
  ushort* ig    = whhb + WEL;
  ushort* hinit = ig + (size_t)TCHUNK * NBATCH * NGATE;
  ushort* h0r   = hinit + 2 * (size_t)BH;
  ushort* h1r   = h0r + 2 * (size_t)BH;
  float*  cbuf  = (float*)(h1r + 2 * (size_t)BH);
  int*    bar   = (int*)(cbuf + 2 * (size_t)BH);

  const size_t need = ((size_t)TBH + 2 * WEL + (size_t)TCHUNK * NBATCH * NGATE
                       + 6 * (size_t)BH) * 2 + 2 * (size_t)BH * 4 + 1024;
  if (ws_size < need) return;  // loud failure: d_out stays poisoned

  { int n = TBH;          k_f32_to_bf16<<<(n / 4 + 255) / 256, 256, 0, stream>>>(x, xb, n); }
  { int n = (int)WEL;     k_f32_to_bf16<<<(n / 4 + 255) / 256, 256, 0, stream>>>(w_ih, wihb, n); }
  { int n = (int)WEL;     k_f32_to_bf16<<<(n / 4 + 255) / 256, 256, 0, stream>>>(w_hh, whhb, n); }
  { int n = 2 * BH;       k_f32_to_bf16<<<(n / 4 + 255) / 256, 256, 0, stream>>>(h0, hinit, n); }
  k_copy_f32<<<(2 * BH / 4 + 255) / 256, 256, 0, stream>>>(c0, cbuf, 2 * BH);

  ScanP sp;
  sp.wih1 = wihb + (size_t)NGATE * HID;
  sp.whh0 = whhb;
  sp.whh1 = whhb + (size_t)NGATE * HID;
  sp.ig = ig; sp.hinit = hinit;
  sp.h0r = h0r; sp.h1r = h1r; sp.cbuf = cbuf;
  sp.bi1 = b_ih + NGATE; sp.bh1 = b_hh + NGATE;
  sp.out = out; sp.bar = bar;

  const int bounds[5] = {0, 128, 256, 384, 513};
  for (int c = 0; c < 4; ++c) {
    k_zero<<<1, 256, 0, stream>>>(bar, 256);
    k_gemm_ig<<<dim3(64, 32), 256, 0, stream>>>(
        xb + (size_t)c * TCHUNK * NBATCH * HID, wihb, b_ih, b_hh, ig);
    sp.s0 = bounds[c]; sp.s1 = bounds[c + 1];
    void* kp[1] = {&sp};
    hipLaunchCooperativeKernel(reinterpret_cast<void*>(&k_scan),
                               dim3(NBLK), dim3(256), kp, 0, stream);
  }
}